// Round 8
// baseline (683.732 us; speedup 1.0000x reference)
//
#include <hip/hip_runtime.h>
#include <hip/hip_bf16.h>
#include <math.h>

#define NB 4
#define NN 1500
#define KNB 30
#define H 128
#define NHEADS 4
#define FFH 512
#define NODE_FEAT 1024
#define NROWS (NB*NN)
#define LN_EPS 1e-6f

typedef __attribute__((ext_vector_type(8))) short s8v;   // 8 bf16 = 4 VGPRs (MFMA A/B frag)
typedef __attribute__((ext_vector_type(4))) float f4v;   // MFMA C/D frag

__device__ __forceinline__ float bf_lo(unsigned u){ union{unsigned i; float f;} v; v.i = u<<16; return v.f; }
__device__ __forceinline__ float bf_hi(unsigned u){ union{unsigned i; float f;} v; v.i = u & 0xffff0000u; return v.f; }

// ---------------------------------------------------------------- topk (radix select)
__device__ __forceinline__ void find_bucket30(
    const int* hist, int base0, int t, int lane, int wave,
    int* wsum, int* res)
{
    int h[16], s = 0;
#pragma unroll
    for (int i = 0; i < 16; i++) { h[i] = hist[(i<<8)|t]; s += h[i]; }
    int inc = s;
#pragma unroll
    for (int off = 1; off < 64; off <<= 1) {
        int o = __shfl_up(inc, off, 64);
        if (lane >= off) inc += o;
    }
    if (lane == 63) wsum[wave] = inc;
    __syncthreads();
    int base = base0 + inc - s;
    for (int w = 0; w < wave; w++) base += wsum[w];
    if (base < KNB && base + s >= KNB) {
        int running = base;
#pragma unroll
        for (int i = 0; i < 16; i++) {
            if (running < KNB && running + h[i] >= KNB) { res[0] = (t<<4)|i; res[1] = running; break; }
            running += h[i];
        }
    }
    __syncthreads();
}

__global__ __launch_bounds__(256) void topk_kernel(
    const float* __restrict__ X, const float* __restrict__ mask,
    int* __restrict__ E_idx, float* __restrict__ D_nb)
{
    int row = blockIdx.x;            // b*NN + i
    int b = row / NN;
    int t = threadIdx.x;
    int wave = t >> 6, lane = t & 63;
    __shared__ float d_adj[NN];
    __shared__ int   hist[4096];
    __shared__ float redw[4];
    __shared__ int   wsum[4];
    __shared__ int   res[2];
    __shared__ int   cand[64];
    __shared__ int   ncand;

    float xi0 = X[row*3+0], xi1 = X[row*3+1], xi2 = X[row*3+2];
    float mi = mask[row];

    float dr[6], m2r[6];
    float lmax = -1e30f;
#pragma unroll
    for (int q = 0; q < 6; q++) {
        int j = t + q*256;
        float d = 0.f, m2 = 0.f;
        if (j < NN) {
            float dx = xi0 - X[(b*NN+j)*3+0];
            float dy = xi1 - X[(b*NN+j)*3+1];
            float dz = xi2 - X[(b*NN+j)*3+2];
            d  = sqrtf(dx*dx + dy*dy + dz*dz + 1e-6f);
            m2 = mi * mask[b*NN+j];
            lmax = fmaxf(lmax, m2*d);
        }
        dr[q] = d; m2r[q] = m2;
    }
    for (int q = t; q < 4096; q += 256) hist[q] = 0;
#pragma unroll
    for (int off = 32; off > 0; off >>= 1)
        lmax = fmaxf(lmax, __shfl_xor(lmax, off, 64));
    if (lane == 0) redw[wave] = lmax;
    if (t == 0) ncand = 0;
    __syncthreads();
    float rowmax = fmaxf(fmaxf(redw[0], redw[1]), fmaxf(redw[2], redw[3]));

    unsigned kreg[6];
#pragma unroll
    for (int q = 0; q < 6; q++) {
        int j = t + q*256;
        if (j < NN) {
            float dv = m2r[q]*dr[q] + (1.0f - m2r[q])*rowmax;   // >= 0
            d_adj[j] = dv;
            unsigned key = __float_as_uint(dv);
            kreg[q] = key;
            unsigned bkt = key >> 20;
            atomicAdd(&hist[((bkt & 15) << 8) | (bkt >> 4)], 1);
        } else kreg[q] = 0xFFFFFFFFu;
    }
    __syncthreads();

    find_bucket30(hist, 0, t, lane, wave, wsum, res);
    int B1 = res[0], nb1 = res[1];

    for (int q = t; q < 4096; q += 256) hist[q] = 0;
    __syncthreads();
#pragma unroll
    for (int q = 0; q < 6; q++) {
        if ((kreg[q] >> 20) == (unsigned)B1) {
            unsigned bkt = (kreg[q] >> 8) & 0xFFF;
            atomicAdd(&hist[((bkt & 15) << 8) | (bkt >> 4)], 1);
        }
    }
    __syncthreads();

    find_bucket30(hist, nb1, t, lane, wave, wsum, res);
    unsigned Bfull = ((unsigned)B1 << 12) | (unsigned)res[0];

#pragma unroll
    for (int q = 0; q < 6; q++) {
        if ((kreg[q] >> 8) <= Bfull) {
            int slot = atomicAdd(&ncand, 1);
            if (slot < 64) cand[slot] = t + q*256;
        }
    }
    __syncthreads();

    if (wave == 0) {
        int nc = min(ncand, 64);
        if (lane < nc) {
            int j = cand[lane];
            float v = d_adj[j];
            int rank = 0;
            for (int m = 0; m < nc; m++) {
                int jm = cand[m];
                float vm = d_adj[jm];
                rank += (vm < v || (vm == v && jm < j)) ? 1 : 0;
            }
            if (rank < KNB) {
                E_idx[row*KNB + rank] = j;
                D_nb[row*KNB + rank]  = v;
            }
        }
    }
}

// ---------------------------------------------------------------- W_edge transpose+cast: W_edge_t[n][k] bf16 (128x32)
__global__ __launch_bounds__(256) void wprep_edge_kernel(
    const float* __restrict__ W_edge, __hip_bfloat16* __restrict__ W_edge_t)
{
    int tid = blockIdx.x*256 + threadIdx.x;  // 4096
    int n = tid >> 5, k = tid & 31;
    W_edge_t[tid] = __float2bfloat16(W_edge[k*H + n]);
}

// ---------------------------------------------------------------- edge features -> E_ln (bf16), MFMA
__global__ __launch_bounds__(256) void edge_kernel(
    const int* __restrict__ E_idx, const float* __restrict__ D_nb,
    const __hip_bfloat16* __restrict__ W_edge_t, const float* __restrict__ ln_g,
    const float* __restrict__ ln_b, __hip_bfloat16* __restrict__ E_ln)
{
    int g0 = blockIdx.x * 2;
    int t = threadIdx.x;
    int wave = t >> 6, lane = t & 63, lm = lane & 15, lq = lane >> 4;
    __shared__ __hip_bfloat16 Es[64*136];

    int row = wave*16 + lm;
    int rr = row < 60 ? row : 59;
    int node = g0 + (rr >= KNB ? 1 : 0);
    int e = node*KNB + (rr >= KNB ? rr - KNB : rr);
    float drel = (float)(E_idx[e] - (node % NN));
    float dnb  = D_nb[e];

    const float FR[8] = {1.f, 0.31622776601683794f, 0.1f, 0.031622776601683794f,
                         0.01f, 0.0031622776601683794f, 0.001f, 0.00031622776601683794f};
    union { s8v v; __hip_bfloat16 h[8]; } af;
    if (lq == 0) {
#pragma unroll
        for (int j = 0; j < 8; j++) af.h[j] = __float2bfloat16(cosf(drel*FR[j]));
    } else if (lq == 1) {
#pragma unroll
        for (int j = 0; j < 8; j++) af.h[j] = __float2bfloat16(sinf(drel*FR[j]));
    } else {
        int f0 = (lq-2)*8;
#pragma unroll
        for (int j = 0; j < 8; j++) {
            float mu = (20.0f/15.0f) * (float)(f0+j);
            float z = (dnb - mu) * 0.8f;
            af.h[j] = __float2bfloat16(expf(-z*z));
        }
    }

    f4v acc[8];
#pragma unroll
    for (int nt = 0; nt < 8; nt++) {
        s8v bf = *(const s8v*)&W_edge_t[(nt*16+lm)*32 + lq*8];
        f4v z = {0.f,0.f,0.f,0.f};
        acc[nt] = __builtin_amdgcn_mfma_f32_16x16x32_bf16(af.v, bf, z, 0,0,0);
    }

    float gv[8], bv[8];
#pragma unroll
    for (int nt = 0; nt < 8; nt++) { gv[nt] = ln_g[nt*16+lm]; bv[nt] = ln_b[nt*16+lm]; }
#pragma unroll
    for (int r = 0; r < 4; r++) {
        float sm = 0.f, sq = 0.f;
#pragma unroll
        for (int nt = 0; nt < 8; nt++) { float x = acc[nt][r]; sm += x; sq += x*x; }
#pragma unroll
        for (int m = 1; m < 16; m <<= 1) {
            sm += __shfl_xor(sm, m, 64);
            sq += __shfl_xor(sq, m, 64);
        }
        float mu = sm * (1.0f/H);
        float rs = rsqrtf(sq*(1.0f/H) - mu*mu + LN_EPS);
        int erow = wave*16 + lq*4 + r;
#pragma unroll
        for (int nt = 0; nt < 8; nt++)
            Es[erow*136 + nt*16 + lm] =
                __float2bfloat16(gv[nt]*(acc[nt][r]-mu)*rs + bv[nt]);
    }
    __syncthreads();

    __hip_bfloat16* dst = E_ln + (size_t)g0*KNB*H;
    for (int q = t; q < 960; q += 256) {
        int r = q >> 4, c8 = (q & 15) * 8;
        *(s8v*)&dst[r*H + c8] = *(const s8v*)&Es[r*136 + c8];
    }
}

// ---------------------------------------------------------------- W_v transpose+cast: Wv_t[n][k] bf16
__global__ __launch_bounds__(256) void wprep_v_kernel(
    const float* __restrict__ W_v, __hip_bfloat16* __restrict__ Wv_t)
{
    int tid = blockIdx.x*256 + threadIdx.x;  // 131072
    int n = tid & 127, k = tid >> 7;
    Wv_t[(size_t)n*NODE_FEAT + k] = __float2bfloat16(W_v[k*H + n]);
}

// ---------------------------------------------------------------- h_V = V @ W_v + b_v  (MFMA)
// + fused layer-0 node projections P = hv @ [Wq|Wk_bot|Wv_bot]
__global__ __launch_bounds__(256) void hv_init_kernel(
    const float* __restrict__ V, const __hip_bfloat16* __restrict__ Wv_t,
    const float* __restrict__ b_v, float* __restrict__ hv,
    const __hip_bfloat16* __restrict__ Wn_t, float* __restrict__ P)
{
    int row0 = blockIdx.x * 16;
    int t = threadIdx.x;
    int wave = t >> 6, lane = t & 63, lm = lane & 15, lq = lane >> 4;
    __shared__ __hip_bfloat16 Vs[16*1032];   // pitch 1032 (2-way bank alias only)
    __shared__ __hip_bfloat16 zs[16*136];

    for (int q = t; q < 4096; q += 256) {
        int r = q >> 8, c4 = (q & 255) * 4;
        float4 v4 = *(const float4*)&V[(size_t)(row0+r)*NODE_FEAT + c4];
        __hip_bfloat16* d = &Vs[r*1032 + c4];
        d[0] = __float2bfloat16(v4.x);
        d[1] = __float2bfloat16(v4.y);
        d[2] = __float2bfloat16(v4.z);
        d[3] = __float2bfloat16(v4.w);
    }
    __syncthreads();

#pragma unroll
    for (int ntl = 0; ntl < 2; ntl++) {
        int nt = wave*2 + ntl;
        f4v acc = {0.f,0.f,0.f,0.f};
        for (int ks = 0; ks < 32; ks++) {
            s8v af = *(const s8v*)&Vs[lm*1032 + ks*32 + lq*8];
            s8v bf = *(const s8v*)&Wv_t[(size_t)(nt*16+lm)*NODE_FEAT + ks*32 + lq*8];
            acc = __builtin_amdgcn_mfma_f32_16x16x32_bf16(af, bf, acc, 0,0,0);
        }
        int cc = nt*16 + lm;
        float b = b_v[cc];
#pragma unroll
        for (int r = 0; r < 4; r++) {
            int rr = lq*4 + r;
            float v = acc[r] + b;
            hv[(size_t)(row0+rr)*H + cc] = v;
            zs[rr*136+cc] = __float2bfloat16(v);
        }
    }
    __syncthreads();

    for (int ntl = 0; ntl < 6; ntl++) {
        int nt = wave*6 + ntl;
        f4v acc = {0.f,0.f,0.f,0.f};
#pragma unroll
        for (int ks = 0; ks < 4; ks++) {
            s8v af = *(const s8v*)&zs[lm*136 + ks*32 + lq*8];
            s8v bf = *(const s8v*)&Wn_t[(size_t)(nt*16+lm)*H + ks*32 + lq*8];
            acc = __builtin_amdgcn_mfma_f32_16x16x32_bf16(af, bf, acc, 0,0,0);
        }
        int cc = nt*16 + lm;
#pragma unroll
        for (int r = 0; r < 4; r++)
            P[(size_t)(row0 + lq*4 + r)*384 + cc] = acc[r];
    }
}

// ---------------------------------------------------------------- fold W_e into per-layer edge K/V
__global__ __launch_bounds__(128) void wprep_kv_kernel(
    const float* __restrict__ W_e, const float* __restrict__ b_e,
    const float* __restrict__ Wk, const float* __restrict__ Wv,
    __hip_bfloat16* __restrict__ Wt_kv, float* __restrict__ bias_kv)
{
    int l = blockIdx.x >> 8;
    int n = blockIdx.x & 255;
    int t = threadIdx.x;             // t = k (0..127)
    int col = n & 127;
    const float* W = (n < 128) ? (Wk + l*2*H*H) : (Wv + l*2*H*H);
    __shared__ float wcol[128];
    wcol[t] = W[t*H + col];          // rows 0..127 = h_E block
    __syncthreads();
    float a = 0.f;
    for (int c = 0; c < H; c += 4) {
        float4 we = *(const float4*)&W_e[t*H + c];
        a += we.x*wcol[c] + we.y*wcol[c+1] + we.z*wcol[c+2] + we.w*wcol[c+3];
    }
    Wt_kv[(size_t)(l*256 + n)*H + t] = __float2bfloat16(a);
    if (t == 0) {
        float bsum = 0.f;
        for (int c = 0; c < H; c++) bsum += b_e[c]*wcol[c];
        bias_kv[l*256 + n] = bsum;
    }
}

// ---------------------------------------------------------------- transpose+cast weights to bf16 [n][k]
__global__ __launch_bounds__(256) void wprep_post_kernel(
    const float* __restrict__ Wo, const float* __restrict__ Wf1,
    const float* __restrict__ Wf2, const float* __restrict__ Wq,
    const float* __restrict__ Wk, const float* __restrict__ Wv,
    __hip_bfloat16* __restrict__ Wo_t, __hip_bfloat16* __restrict__ Wf1_t,
    __hip_bfloat16* __restrict__ Wf2_t, __hip_bfloat16* __restrict__ Wn_t)
{
    int id = blockIdx.x*256 + threadIdx.x;   // < 786432
    int l = id / 196608;
    int r = id - l*196608;
    float v; __hip_bfloat16* dst;
    if (r < 16384) {
        int n = r >> 7, k = r & 127;
        v = Wo[l*16384 + k*128 + n];
        dst = Wo_t + l*16384 + r;
    } else if (r < 81920) {
        int rr = r - 16384;
        int n = rr >> 7, k = rr & 127;
        v = Wf1[l*65536 + k*512 + n];
        dst = Wf1_t + l*65536 + rr;
    } else if (r < 147456) {
        int rr = r - 81920;
        int n = rr >> 9, k = rr & 511;
        v = Wf2[l*65536 + k*128 + n];
        dst = Wf2_t + l*65536 + rr;
    } else {
        int rr = r - 147456;
        int n = rr >> 7, k = rr & 127;
        if (n < 128)      v = Wq[l*16384 + k*128 + n];
        else if (n < 256) v = Wk[l*32768 + (128+k)*128 + (n-128)];
        else              v = Wv[l*32768 + (128+k)*128 + (n-256)];
        dst = Wn_t + l*49152 + rr;
    }
    *dst = __float2bfloat16(v);
}

// ---------------------------------------------------------------- attention: 2 nodes/block
// A-frags read directly from E_ln (no LDS staging); parallel softmax.
__global__ __launch_bounds__(256) void attn_kernel(
    const __hip_bfloat16* __restrict__ E_ln, const __hip_bfloat16* __restrict__ Wt,
    const float* __restrict__ bias_kv,
    float* __restrict__ P, const int* __restrict__ E_idx,
    const float* __restrict__ mask)
{
    int g0 = blockIdx.x * 2;
    int t = threadIdx.x;
    int wave = t >> 6, lane = t & 63, lm = lane & 15, lq = lane >> 4;
    __shared__ __hip_bfloat16 KVs[60*264];    // K|V rows, pitch 264 bf16
    __shared__ float Qs[2*H];
    __shared__ float att_s[2*120];
    __shared__ float mv_s[60];
    __shared__ int   nbr[60];

    if (t < 60) {
        int gn = g0 + t/30;
        int b = gn / NN;
        int idx = E_idx[gn*KNB + (t%30)];
        nbr[t]  = b*NN + idx;
        mv_s[t] = mask[gn] * mask[b*NN + idx];
    }
    {
        int node = t >> 7, c = t & 127;
        Qs[t] = P[(size_t)(g0+node)*384 + c];
    }
    __syncthreads();

    // MFMA: wave w handles n-tiles 4w..4w+3; A-frags direct from global E_ln
    {
        int cb = wave*64 + lm;
        const __hip_bfloat16* wb = Wt + (size_t)cb*H + lq*8;
        const __hip_bfloat16* hebase = E_ln + (size_t)g0*KNB*H + lm*H + lq*8;
        s8v bfr[4][4];
#pragma unroll
        for (int nt = 0; nt < 4; nt++)
#pragma unroll
            for (int ks = 0; ks < 4; ks++)
                bfr[nt][ks] = *(const s8v*)(wb + nt*16*H + ks*32);
        float bias0 = bias_kv[cb], bias1 = bias_kv[cb+16];
        float bias2 = bias_kv[cb+32], bias3 = bias_kv[cb+48];
#pragma unroll
        for (int mt = 0; mt < 4; mt++) {
            f4v a0 = {0.f,0.f,0.f,0.f}, a1 = a0, a2 = a0, a3 = a0;
#pragma unroll
            for (int ks = 0; ks < 4; ks++) {
                s8v af = *(const s8v*)&hebase[mt*16*H + ks*32];
                a0 = __builtin_amdgcn_mfma_f32_16x16x32_bf16(af, bfr[0][ks], a0, 0,0,0);
                a1 = __builtin_amdgcn_mfma_f32_16x16x32_bf16(af, bfr[1][ks], a1, 0,0,0);
                a2 = __builtin_amdgcn_mfma_f32_16x16x32_bf16(af, bfr[2][ks], a2, 0,0,0);
                a3 = __builtin_amdgcn_mfma_f32_16x16x32_bf16(af, bfr[3][ks], a3, 0,0,0);
            }
            int rbase = mt*16 + lq*4;
#pragma unroll
            for (int r = 0; r < 4; r++) {
                int row = rbase + r;
                if (row < 60) {
                    const float* pb = P + (size_t)nbr[row]*384 + 128 + cb;
                    KVs[row*264 + cb     ] = __float2bfloat16(a0[r] + bias0 + pb[0]);
                    KVs[row*264 + cb + 16] = __float2bfloat16(a1[r] + bias1 + pb[16]);
                    KVs[row*264 + cb + 32] = __float2bfloat16(a2[r] + bias2 + pb[32]);
                    KVs[row*264 + cb + 48] = __float2bfloat16(a3[r] + bias3 + pb[48]);
                }
            }
        }
    }
    __syncthreads();

    // logits (b128 LDS reads)
    if (t < 240) {
        int node = t / 120, tt = t % 120;
        int h = tt / 30, kk = tt % 30;
        int r = node*30 + kk;
        const uint4* kp = (const uint4*)&KVs[r*264 + h*32];
        const float* qp = &Qs[node*128 + h*32];
        float a = 0.f;
#pragma unroll
        for (int j = 0; j < 4; j++) {
            uint4 u = kp[j];
            const float* q8 = qp + j*8;
            a += q8[0]*bf_lo(u.x) + q8[1]*bf_hi(u.x)
               + q8[2]*bf_lo(u.y) + q8[3]*bf_hi(u.y)
               + q8[4]*bf_lo(u.z) + q8[5]*bf_hi(u.z)
               + q8[6]*bf_lo(u.w) + q8[7]*bf_hi(u.w);
        }
        att_s[node*120 + h*30 + kk] =
            (mv_s[r] > 0.f) ? a*0.17677669529663687f : -3.4028235e38f;
    }
    __syncthreads();

    // parallel softmax: wave w = node w (w<2), 16 lanes per head, 2 entries/lane
    if (wave < 2) {
        int node = wave, h = lq, j = lm;
        float* ap = &att_s[node*120 + h*30];
        const float* mp = &mv_s[node*30];
        float a0 = ap[j];
        float a1 = (j+16 < KNB) ? ap[j+16] : -3.4028235e38f;
        float mx = fmaxf(a0, a1);
#pragma unroll
        for (int m = 1; m < 16; m <<= 1) mx = fmaxf(mx, __shfl_xor(mx, m, 64));
        float e0 = __expf(a0 - mx);
        float e1 = (j+16 < KNB) ? __expf(a1 - mx) : 0.f;
        float s = e0 + e1;
#pragma unroll
        for (int m = 1; m < 16; m <<= 1) s += __shfl_xor(s, m, 64);
        float inv = 1.0f / s;
        ap[j] = e0 * inv * mp[j];
        if (j+16 < KNB) ap[j+16] = e1 * inv * mp[j+16];
    }
    __syncthreads();

    // upd = sum_k att * V; write into P Q-slots
    {
        int node = t >> 7, c = t & 127;
        const float* ap = &att_s[node*120 + (c>>5)*30];
        float u = 0.f;
        for (int kk = 0; kk < KNB; kk++)
            u += ap[kk] * __bfloat162float(KVs[(node*30+kk)*264 + 128 + c]);
        P[(size_t)(g0+node)*384 + c] = u;
    }
}

// ---------------------------------------------------------------- Wo + LN1 + FF + LN2 (+ next-layer node proj), MFMA
// 8 rows/block (grid 750); MFMA m-tiles half-filled, rows 8-15 garbage never stored.
__global__ __launch_bounds__(256) void post_kernel(
    float* __restrict__ hv, float* __restrict__ P,
    const float* __restrict__ mask,
    const __hip_bfloat16* __restrict__ Wo_t,
    const float* __restrict__ ln1g, const float* __restrict__ ln1b,
    const float* __restrict__ ln2g, const float* __restrict__ ln2b,
    const __hip_bfloat16* __restrict__ Wf1_t, const float* __restrict__ bf1,
    const __hip_bfloat16* __restrict__ Wf2_t, const float* __restrict__ bf2,
    const __hip_bfloat16* __restrict__ Wn_t)
{
    int row0 = blockIdx.x * 8;
    int t = threadIdx.x;
    int wave = t >> 6, lane = t & 63, lm = lane & 15, lq = lane >> 4;

    __shared__ __hip_bfloat16 Aus[16*136];   // upd bf16 (rows 0..7 valid)
    __shared__ float xs[16*132];             // fp32 working rows (rows 0..7 valid)
    __shared__ __hip_bfloat16 ys[16*136];    // LN1 out bf16
    __shared__ __hip_bfloat16 t1[16*520];    // relu(FF1) bf16
    __shared__ __hip_bfloat16 zs[16*136];    // hv_out bf16
    __shared__ float ps[128], pq[128];
    __shared__ float mu_s[8], rs_s[8];

    // 1. load upd (attn output, in P's Q slots) - rows 0..7
    for (int q = t; q < 1024; q += 256) {
        int r = q >> 7, c = q & 127;
        Aus[r*136+c] = __float2bfloat16(P[(size_t)(row0+r)*384 + c]);
    }
    __syncthreads();

    // 2. x = hv + upd @ Wo
    for (int ntl = 0; ntl < 2; ntl++) {
        int nt = wave*2 + ntl;
        f4v acc = {0.f,0.f,0.f,0.f};
#pragma unroll
        for (int ks = 0; ks < 4; ks++) {
            s8v af = *(const s8v*)&Aus[lm*136 + ks*32 + lq*8];
            s8v bf = *(const s8v*)&Wo_t[(nt*16+lm)*128 + ks*32 + lq*8];
            acc = __builtin_amdgcn_mfma_f32_16x16x32_bf16(af, bf, acc, 0,0,0);
        }
        if (lq < 2) {
            int cc = nt*16 + lm;
#pragma unroll
            for (int r = 0; r < 4; r++) {
                int rr = lq*4 + r;
                xs[rr*132+cc] = hv[(size_t)(row0+rr)*128 + cc] + acc[r];
            }
        }
    }
    __syncthreads();

    // 3. LN1 -> xs (fp32) and ys (bf16)
    if (t < 128) {
        int r = t >> 4, s = t & 15;
        float4 a = *(const float4*)&xs[r*132 + s*8];
        float4 b = *(const float4*)&xs[r*132 + s*8 + 4];
        ps[t] = a.x+a.y+a.z+a.w + b.x+b.y+b.z+b.w;
        pq[t] = a.x*a.x+a.y*a.y+a.z*a.z+a.w*a.w + b.x*b.x+b.y*b.y+b.z*b.z+b.w*b.w;
    }
    __syncthreads();
    if (t < 8) {
        float sm = 0.f, sq = 0.f;
        for (int s = 0; s < 16; s++) { sm += ps[t*16+s]; sq += pq[t*16+s]; }
        float mu = sm*(1.0f/H);
        mu_s[t] = mu;
        rs_s[t] = rsqrtf(sq*(1.0f/H) - mu*mu + LN_EPS);
    }
    __syncthreads();
    for (int q = t; q < 1024; q += 256) {
        int r = q >> 7, c = q & 127;
        float v = ln1g[c]*(xs[r*132+c]-mu_s[r])*rs_s[r] + ln1b[c];
        xs[r*132+c] = v;
        ys[r*136+c] = __float2bfloat16(v);
    }
    __syncthreads();

    // 4. FF1 + ReLU -> t1 (bf16)
    for (int ntl = 0; ntl < 8; ntl++) {
        int nt = wave*8 + ntl;
        f4v acc = {0.f,0.f,0.f,0.f};
#pragma unroll
        for (int ks = 0; ks < 4; ks++) {
            s8v af = *(const s8v*)&ys[lm*136 + ks*32 + lq*8];
            s8v bf = *(const s8v*)&Wf1_t[(size_t)(nt*16+lm)*128 + ks*32 + lq*8];
            acc = __builtin_amdgcn_mfma_f32_16x16x32_bf16(af, bf, acc, 0,0,0);
        }
        if (lq < 2) {
            int cc = nt*16 + lm;
            float b = bf1[cc];
#pragma unroll
            for (int r = 0; r < 4; r++)
                t1[(lq*4+r)*520 + cc] = __float2bfloat16(fmaxf(acc[r]+b, 0.f));
        }
    }
    __syncthreads();

    // 5. x2 = LN1out + FF2(t1) + b
    for (int ntl = 0; ntl < 2; ntl++) {
        int nt = wave*2 + ntl;
        f4v acc = {0.f,0.f,0.f,0.f};
#pragma unroll
        for (int ks = 0; ks < 16; ks++) {
            s8v af = *(const s8v*)&t1[lm*520 + ks*32 + lq*8];
            s8v bf = *(const s8v*)&Wf2_t[(size_t)(nt*16+lm)*512 + ks*32 + lq*8];
            acc = __builtin_amdgcn_mfma_f32_16x16x32_bf16(af, bf, acc, 0,0,0);
        }
        if (lq < 2) {
            int cc = nt*16 + lm;
            float b = bf2[cc];
#pragma unroll
            for (int r = 0; r < 4; r++) {
                int rr = lq*4 + r;
                xs[rr*132+cc] = xs[rr*132+cc] + acc[r] + b;
            }
        }
    }
    __syncthreads();

    // 6. LN2 + mask -> hv (global) and zs (bf16)
    if (t < 128) {
        int r = t >> 4, s = t & 15;
        float4 a = *(const float4*)&xs[r*132 + s*8];
        float4 b = *(const float4*)&xs[r*132 + s*8 + 4];
        ps[t] = a.x+a.y+a.z+a.w + b.x+b.y+b.z+b.w;
        pq[t] = a.x*a.x+a.y*a.y+a.z*a.z+a.w*a.w + b.x*b.x+b.y*b.y+b.z*b.z+b.w*b.w;
    }
    __syncthreads();
    if (t < 8) {
        float sm = 0.f, sq = 0.f;
        for (int s = 0; s < 16; s++) { sm += ps[t*16+s]; sq += pq[t*16+s]; }
        float mu = sm*(1.0f/H);
        mu_s[t] = mu;
        rs_s[t] = rsqrtf(sq*(1.0f/H) - mu*mu + LN_EPS);
    }
    __syncthreads();
    for (int q = t; q < 1024; q += 256) {
        int r = q >> 7, c = q & 127;
        float v = mask[row0+r]*(ln2g[c]*(xs[r*132+c]-mu_s[r])*rs_s[r] + ln2b[c]);
        hv[(size_t)(row0+r)*128 + c] = v;
        zs[r*136+c] = __float2bfloat16(v);
    }
    __syncthreads();

    // 7. next-layer node projections: P = hv_out @ [Wq|Wk_bot|Wv_bot]
    if (Wn_t) {
        for (int ntl = 0; ntl < 6; ntl++) {
            int nt = wave*6 + ntl;
            f4v acc = {0.f,0.f,0.f,0.f};
#pragma unroll
            for (int ks = 0; ks < 4; ks++) {
                s8v af = *(const s8v*)&zs[lm*136 + ks*32 + lq*8];
                s8v bf = *(const s8v*)&Wn_t[(size_t)(nt*16+lm)*128 + ks*32 + lq*8];
                acc = __builtin_amdgcn_mfma_f32_16x16x32_bf16(af, bf, acc, 0,0,0);
            }
            if (lq < 2) {
                int cc = nt*16 + lm;
#pragma unroll
                for (int r = 0; r < 4; r++)
                    P[(size_t)(row0 + lq*4 + r)*384 + cc] = acc[r];
            }
        }
    }
}

// ---------------------------------------------------------------- final projection
__global__ __launch_bounds__(64) void out_kernel(
    const float* __restrict__ hv, const float* __restrict__ W_out,
    const float* __restrict__ b_out, float* __restrict__ out)
{
    int row = blockIdx.x;
    int t = threadIdx.x;
    float a = hv[row*H+t]*W_out[t] + hv[row*H+t+64]*W_out[t+64];
#pragma unroll
    for (int s = 32; s > 0; s >>= 1) a += __shfl_down(a, s, 64);
    if (t == 0) out[row] = a + b_out[0];
}

// ---------------------------------------------------------------- launch
extern "C" void kernel_launch(void* const* d_in, const int* in_sizes, int n_in,
                              void* d_out, int out_size, void* d_ws, size_t ws_size,
                              hipStream_t stream)
{
    const float* X      = (const float*)d_in[0];
    const float* V      = (const float*)d_in[1];
    const float* mask   = (const float*)d_in[2];
    const float* W_v    = (const float*)d_in[3];
    const float* b_v    = (const float*)d_in[4];
    const float* W_e    = (const float*)d_in[5];
    const float* b_e    = (const float*)d_in[6];
    const float* W_edge = (const float*)d_in[7];
    const float* ln_e_g = (const float*)d_in[8];
    const float* ln_e_b = (const float*)d_in[9];
    const float* Wq     = (const float*)d_in[10];
    const float* Wk     = (const float*)d_in[11];
    const float* Wv_a   = (const float*)d_in[12];
    const float* Wo     = (const float*)d_in[13];
    const float* ln1g   = (const float*)d_in[14];
    const float* ln1b   = (const float*)d_in[15];
    const float* ln2g   = (const float*)d_in[16];
    const float* ln2b   = (const float*)d_in[17];
    const float* Wf1    = (const float*)d_in[18];
    const float* bf1    = (const float*)d_in[19];
    const float* Wf2    = (const float*)d_in[20];
    const float* bf2    = (const float*)d_in[21];
    const float* W_out  = (const float*)d_in[22];
    const float* b_out  = (const float*)d_in[23];
    float* out = (float*)d_out;

    // workspace layout (same as R7)
    char* ws = (char*)d_ws;
    int*            E_idx    = (int*)ws;
    float*          D_nb     = (float*)(ws + 720000);
    __hip_bfloat16* E_ln     = (__hip_bfloat16*)(ws + 1440000);
    float*          hv       = (float*)(ws + 47520000);
    __hip_bfloat16* Wt_kv    = (__hip_bfloat16*)(ws + 50592000);
    float*          bias_kv  = (float*)(ws + 50854144);
    __hip_bfloat16* Wn_t     = (__hip_bfloat16*)(ws + 50858240);
    __hip_bfloat16* Wo_t     = (__hip_bfloat16*)(ws + 51251456);
    __hip_bfloat16* Wf1_t    = (__hip_bfloat16*)(ws + 51382528);
    __hip_bfloat16* Wf2_t    = (__hip_bfloat16*)(ws + 51906816);
    __hip_bfloat16* Wv_t     = (__hip_bfloat16*)(ws + 52431104);
    __hip_bfloat16* W_edge_t = (__hip_bfloat16*)(ws + 52693248);
    float*          P        = (float*)(ws + 53664000);

    topk_kernel<<<NROWS, 256, 0, stream>>>(X, mask, E_idx, D_nb);
    wprep_edge_kernel<<<16, 256, 0, stream>>>(W_edge, W_edge_t);
    edge_kernel<<<NROWS/2, 256, 0, stream>>>(E_idx, D_nb, W_edge_t, ln_e_g, ln_e_b, E_ln);
    wprep_kv_kernel<<<1024, 128, 0, stream>>>(W_e, b_e, Wk, Wv_a, Wt_kv, bias_kv);
    wprep_post_kernel<<<3072, 256, 0, stream>>>(Wo, Wf1, Wf2, Wq, Wk, Wv_a,
                                                Wo_t, Wf1_t, Wf2_t, Wn_t);
    wprep_v_kernel<<<512, 256, 0, stream>>>(W_v, Wv_t);
    hv_init_kernel<<<NROWS/16, 256, 0, stream>>>(V, Wv_t, b_v, hv, Wn_t, P);

    for (int l = 0; l < 4; l++) {
        attn_kernel<<<NROWS/2, 256, 0, stream>>>(
            E_ln, Wt_kv + (size_t)l*256*H, bias_kv + l*256, P, E_idx, mask);
        post_kernel<<<NROWS/8, 256, 0, stream>>>(
            hv, P, mask, Wo_t + l*16384,
            ln1g + l*H, ln1b + l*H, ln2g + l*H, ln2b + l*H,
            Wf1_t + (size_t)l*65536, bf1 + l*FFH,
            Wf2_t + (size_t)l*65536, bf2 + l*H,
            (l < 3) ? (Wn_t + (size_t)(l+1)*49152) : (const __hip_bfloat16*)nullptr);
    }
    out_kernel<<<NROWS, 64, 0, stream>>>(hv, W_out, b_out, out);
}

// Round 9
// 534.904 us; speedup vs baseline: 1.2782x; 1.2782x over previous
//
#include <hip/hip_runtime.h>
#include <hip/hip_bf16.h>
#include <math.h>

#define NB 4
#define NN 1500
#define KNB 30
#define H 128
#define NHEADS 4
#define FFH 512
#define NODE_FEAT 1024
#define NROWS (NB*NN)
#define LN_EPS 1e-6f

typedef __attribute__((ext_vector_type(8))) short s8v;   // 8 bf16 = 4 VGPRs (MFMA A/B frag)
typedef __attribute__((ext_vector_type(4))) float f4v;   // MFMA C/D frag

__device__ __forceinline__ float bf_lo(unsigned u){ union{unsigned i; float f;} v; v.i = u<<16; return v.f; }
__device__ __forceinline__ float bf_hi(unsigned u){ union{unsigned i; float f;} v; v.i = u & 0xffff0000u; return v.f; }

// ---------------------------------------------------------------- topk (radix select)
__device__ __forceinline__ void find_bucket30(
    const int* hist, int base0, int t, int lane, int wave,
    int* wsum, int* res)
{
    int h[16], s = 0;
#pragma unroll
    for (int i = 0; i < 16; i++) { h[i] = hist[(i<<8)|t]; s += h[i]; }
    int inc = s;
#pragma unroll
    for (int off = 1; off < 64; off <<= 1) {
        int o = __shfl_up(inc, off, 64);
        if (lane >= off) inc += o;
    }
    if (lane == 63) wsum[wave] = inc;
    __syncthreads();
    int base = base0 + inc - s;
    for (int w = 0; w < wave; w++) base += wsum[w];
    if (base < KNB && base + s >= KNB) {
        int running = base;
#pragma unroll
        for (int i = 0; i < 16; i++) {
            if (running < KNB && running + h[i] >= KNB) { res[0] = (t<<4)|i; res[1] = running; break; }
            running += h[i];
        }
    }
    __syncthreads();
}

__global__ __launch_bounds__(256) void topk_kernel(
    const float* __restrict__ X, const float* __restrict__ mask,
    int* __restrict__ E_idx, float* __restrict__ D_nb)
{
    int row = blockIdx.x;            // b*NN + i
    int b = row / NN;
    int t = threadIdx.x;
    int wave = t >> 6, lane = t & 63;
    __shared__ float d_adj[NN];
    __shared__ int   hist[4096];
    __shared__ float redw[4];
    __shared__ int   wsum[4];
    __shared__ int   res[2];
    __shared__ int   cand[64];
    __shared__ int   ncand;

    float xi0 = X[row*3+0], xi1 = X[row*3+1], xi2 = X[row*3+2];
    float mi = mask[row];

    float dr[6], m2r[6];
    float lmax = -1e30f;
#pragma unroll
    for (int q = 0; q < 6; q++) {
        int j = t + q*256;
        float d = 0.f, m2 = 0.f;
        if (j < NN) {
            float dx = xi0 - X[(b*NN+j)*3+0];
            float dy = xi1 - X[(b*NN+j)*3+1];
            float dz = xi2 - X[(b*NN+j)*3+2];
            d  = sqrtf(dx*dx + dy*dy + dz*dz + 1e-6f);
            m2 = mi * mask[b*NN+j];
            lmax = fmaxf(lmax, m2*d);
        }
        dr[q] = d; m2r[q] = m2;
    }
    for (int q = t; q < 4096; q += 256) hist[q] = 0;
#pragma unroll
    for (int off = 32; off > 0; off >>= 1)
        lmax = fmaxf(lmax, __shfl_xor(lmax, off, 64));
    if (lane == 0) redw[wave] = lmax;
    if (t == 0) ncand = 0;
    __syncthreads();
    float rowmax = fmaxf(fmaxf(redw[0], redw[1]), fmaxf(redw[2], redw[3]));

    unsigned kreg[6];
#pragma unroll
    for (int q = 0; q < 6; q++) {
        int j = t + q*256;
        if (j < NN) {
            float dv = m2r[q]*dr[q] + (1.0f - m2r[q])*rowmax;   // >= 0
            d_adj[j] = dv;
            unsigned key = __float_as_uint(dv);
            kreg[q] = key;
            unsigned bkt = key >> 20;
            atomicAdd(&hist[((bkt & 15) << 8) | (bkt >> 4)], 1);
        } else kreg[q] = 0xFFFFFFFFu;
    }
    __syncthreads();

    find_bucket30(hist, 0, t, lane, wave, wsum, res);
    int B1 = res[0], nb1 = res[1];

    for (int q = t; q < 4096; q += 256) hist[q] = 0;
    __syncthreads();
#pragma unroll
    for (int q = 0; q < 6; q++) {
        if ((kreg[q] >> 20) == (unsigned)B1) {
            unsigned bkt = (kreg[q] >> 8) & 0xFFF;
            atomicAdd(&hist[((bkt & 15) << 8) | (bkt >> 4)], 1);
        }
    }
    __syncthreads();

    find_bucket30(hist, nb1, t, lane, wave, wsum, res);
    unsigned Bfull = ((unsigned)B1 << 12) | (unsigned)res[0];

#pragma unroll
    for (int q = 0; q < 6; q++) {
        if ((kreg[q] >> 8) <= Bfull) {
            int slot = atomicAdd(&ncand, 1);
            if (slot < 64) cand[slot] = t + q*256;
        }
    }
    __syncthreads();

    if (wave == 0) {
        int nc = min(ncand, 64);
        if (lane < nc) {
            int j = cand[lane];
            float v = d_adj[j];
            int rank = 0;
            for (int m = 0; m < nc; m++) {
                int jm = cand[m];
                float vm = d_adj[jm];
                rank += (vm < v || (vm == v && jm < j)) ? 1 : 0;
            }
            if (rank < KNB) {
                E_idx[row*KNB + rank] = j;
                D_nb[row*KNB + rank]  = v;
            }
        }
    }
}

// ---------------------------------------------------------------- W_edge transpose+cast: W_edge_t[n][k] bf16 (128x32)
__global__ __launch_bounds__(256) void wprep_edge_kernel(
    const float* __restrict__ W_edge, __hip_bfloat16* __restrict__ W_edge_t)
{
    int tid = blockIdx.x*256 + threadIdx.x;  // 4096
    int n = tid >> 5, k = tid & 31;
    W_edge_t[tid] = __float2bfloat16(W_edge[k*H + n]);
}

// ---------------------------------------------------------------- edge features -> E_ln (bf16), MFMA
__global__ __launch_bounds__(256) void edge_kernel(
    const int* __restrict__ E_idx, const float* __restrict__ D_nb,
    const __hip_bfloat16* __restrict__ W_edge_t, const float* __restrict__ ln_g,
    const float* __restrict__ ln_b, __hip_bfloat16* __restrict__ E_ln)
{
    int g0 = blockIdx.x * 2;
    int t = threadIdx.x;
    int wave = t >> 6, lane = t & 63, lm = lane & 15, lq = lane >> 4;
    __shared__ __hip_bfloat16 Es[64*136];

    int row = wave*16 + lm;
    int rr = row < 60 ? row : 59;
    int node = g0 + (rr >= KNB ? 1 : 0);
    int e = node*KNB + (rr >= KNB ? rr - KNB : rr);
    float drel = (float)(E_idx[e] - (node % NN));
    float dnb  = D_nb[e];

    const float FR[8] = {1.f, 0.31622776601683794f, 0.1f, 0.031622776601683794f,
                         0.01f, 0.0031622776601683794f, 0.001f, 0.00031622776601683794f};
    union { s8v v; __hip_bfloat16 h[8]; } af;
    if (lq == 0) {
#pragma unroll
        for (int j = 0; j < 8; j++) af.h[j] = __float2bfloat16(cosf(drel*FR[j]));
    } else if (lq == 1) {
#pragma unroll
        for (int j = 0; j < 8; j++) af.h[j] = __float2bfloat16(sinf(drel*FR[j]));
    } else {
        int f0 = (lq-2)*8;
#pragma unroll
        for (int j = 0; j < 8; j++) {
            float mu = (20.0f/15.0f) * (float)(f0+j);
            float z = (dnb - mu) * 0.8f;
            af.h[j] = __float2bfloat16(expf(-z*z));
        }
    }

    f4v acc[8];
#pragma unroll
    for (int nt = 0; nt < 8; nt++) {
        s8v bf = *(const s8v*)&W_edge_t[(nt*16+lm)*32 + lq*8];
        f4v z = {0.f,0.f,0.f,0.f};
        acc[nt] = __builtin_amdgcn_mfma_f32_16x16x32_bf16(af.v, bf, z, 0,0,0);
    }

    float gv[8], bv[8];
#pragma unroll
    for (int nt = 0; nt < 8; nt++) { gv[nt] = ln_g[nt*16+lm]; bv[nt] = ln_b[nt*16+lm]; }
#pragma unroll
    for (int r = 0; r < 4; r++) {
        float sm = 0.f, sq = 0.f;
#pragma unroll
        for (int nt = 0; nt < 8; nt++) { float x = acc[nt][r]; sm += x; sq += x*x; }
#pragma unroll
        for (int m = 1; m < 16; m <<= 1) {
            sm += __shfl_xor(sm, m, 64);
            sq += __shfl_xor(sq, m, 64);
        }
        float mu = sm * (1.0f/H);
        float rs = rsqrtf(sq*(1.0f/H) - mu*mu + LN_EPS);
        int erow = wave*16 + lq*4 + r;
#pragma unroll
        for (int nt = 0; nt < 8; nt++)
            Es[erow*136 + nt*16 + lm] =
                __float2bfloat16(gv[nt]*(acc[nt][r]-mu)*rs + bv[nt]);
    }
    __syncthreads();

    __hip_bfloat16* dst = E_ln + (size_t)g0*KNB*H;
    for (int q = t; q < 960; q += 256) {
        int r = q >> 4, c8 = (q & 15) * 8;
        *(s8v*)&dst[r*H + c8] = *(const s8v*)&Es[r*136 + c8];
    }
}

// ---------------------------------------------------------------- W_v transpose+cast: Wv_t[n][k] bf16
__global__ __launch_bounds__(256) void wprep_v_kernel(
    const float* __restrict__ W_v, __hip_bfloat16* __restrict__ Wv_t)
{
    int tid = blockIdx.x*256 + threadIdx.x;  // 131072
    int n = tid & 127, k = tid >> 7;
    Wv_t[(size_t)n*NODE_FEAT + k] = __float2bfloat16(W_v[k*H + n]);
}

// ---------------------------------------------------------------- h_V = V @ W_v + b_v  (MFMA)
// + fused layer-0 node projections P = hv @ [Wq|Wk_bot|Wv_bot]
__global__ __launch_bounds__(256) void hv_init_kernel(
    const float* __restrict__ V, const __hip_bfloat16* __restrict__ Wv_t,
    const float* __restrict__ b_v, float* __restrict__ hv,
    const __hip_bfloat16* __restrict__ Wn_t, float* __restrict__ P)
{
    int row0 = blockIdx.x * 16;
    int t = threadIdx.x;
    int wave = t >> 6, lane = t & 63, lm = lane & 15, lq = lane >> 4;
    __shared__ __hip_bfloat16 Vs[16*1032];   // pitch 1032 (2-way bank alias only)
    __shared__ __hip_bfloat16 zs[16*136];

    for (int q = t; q < 4096; q += 256) {
        int r = q >> 8, c4 = (q & 255) * 4;
        float4 v4 = *(const float4*)&V[(size_t)(row0+r)*NODE_FEAT + c4];
        __hip_bfloat16* d = &Vs[r*1032 + c4];
        d[0] = __float2bfloat16(v4.x);
        d[1] = __float2bfloat16(v4.y);
        d[2] = __float2bfloat16(v4.z);
        d[3] = __float2bfloat16(v4.w);
    }
    __syncthreads();

#pragma unroll
    for (int ntl = 0; ntl < 2; ntl++) {
        int nt = wave*2 + ntl;
        f4v acc = {0.f,0.f,0.f,0.f};
        for (int ks = 0; ks < 32; ks++) {
            s8v af = *(const s8v*)&Vs[lm*1032 + ks*32 + lq*8];
            s8v bf = *(const s8v*)&Wv_t[(size_t)(nt*16+lm)*NODE_FEAT + ks*32 + lq*8];
            acc = __builtin_amdgcn_mfma_f32_16x16x32_bf16(af, bf, acc, 0,0,0);
        }
        int cc = nt*16 + lm;
        float b = b_v[cc];
#pragma unroll
        for (int r = 0; r < 4; r++) {
            int rr = lq*4 + r;
            float v = acc[r] + b;
            hv[(size_t)(row0+rr)*H + cc] = v;
            zs[rr*136+cc] = __float2bfloat16(v);
        }
    }
    __syncthreads();

    for (int ntl = 0; ntl < 6; ntl++) {
        int nt = wave*6 + ntl;
        f4v acc = {0.f,0.f,0.f,0.f};
#pragma unroll
        for (int ks = 0; ks < 4; ks++) {
            s8v af = *(const s8v*)&zs[lm*136 + ks*32 + lq*8];
            s8v bf = *(const s8v*)&Wn_t[(size_t)(nt*16+lm)*H + ks*32 + lq*8];
            acc = __builtin_amdgcn_mfma_f32_16x16x32_bf16(af, bf, acc, 0,0,0);
        }
        int cc = nt*16 + lm;
#pragma unroll
        for (int r = 0; r < 4; r++)
            P[(size_t)(row0 + lq*4 + r)*384 + cc] = acc[r];
    }
}

// ---------------------------------------------------------------- fold W_e into per-layer edge K/V
__global__ __launch_bounds__(128) void wprep_kv_kernel(
    const float* __restrict__ W_e, const float* __restrict__ b_e,
    const float* __restrict__ Wk, const float* __restrict__ Wv,
    __hip_bfloat16* __restrict__ Wt_kv, float* __restrict__ bias_kv)
{
    int l = blockIdx.x >> 8;
    int n = blockIdx.x & 255;
    int t = threadIdx.x;             // t = k (0..127)
    int col = n & 127;
    const float* W = (n < 128) ? (Wk + l*2*H*H) : (Wv + l*2*H*H);
    __shared__ float wcol[128];
    wcol[t] = W[t*H + col];          // rows 0..127 = h_E block
    __syncthreads();
    float a = 0.f;
    for (int c = 0; c < H; c += 4) {
        float4 we = *(const float4*)&W_e[t*H + c];
        a += we.x*wcol[c] + we.y*wcol[c+1] + we.z*wcol[c+2] + we.w*wcol[c+3];
    }
    Wt_kv[(size_t)(l*256 + n)*H + t] = __float2bfloat16(a);
    if (t == 0) {
        float bsum = 0.f;
        for (int c = 0; c < H; c++) bsum += b_e[c]*wcol[c];
        bias_kv[l*256 + n] = bsum;
    }
}

// ---------------------------------------------------------------- transpose+cast weights to bf16 [n][k]
__global__ __launch_bounds__(256) void wprep_post_kernel(
    const float* __restrict__ Wo, const float* __restrict__ Wf1,
    const float* __restrict__ Wf2, const float* __restrict__ Wq,
    const float* __restrict__ Wk, const float* __restrict__ Wv,
    __hip_bfloat16* __restrict__ Wo_t, __hip_bfloat16* __restrict__ Wf1_t,
    __hip_bfloat16* __restrict__ Wf2_t, __hip_bfloat16* __restrict__ Wn_t)
{
    int id = blockIdx.x*256 + threadIdx.x;   // < 786432
    int l = id / 196608;
    int r = id - l*196608;
    float v; __hip_bfloat16* dst;
    if (r < 16384) {
        int n = r >> 7, k = r & 127;
        v = Wo[l*16384 + k*128 + n];
        dst = Wo_t + l*16384 + r;
    } else if (r < 81920) {
        int rr = r - 16384;
        int n = rr >> 7, k = rr & 127;
        v = Wf1[l*65536 + k*512 + n];
        dst = Wf1_t + l*65536 + rr;
    } else if (r < 147456) {
        int rr = r - 81920;
        int n = rr >> 9, k = rr & 511;
        v = Wf2[l*65536 + k*128 + n];
        dst = Wf2_t + l*65536 + rr;
    } else {
        int rr = r - 147456;
        int n = rr >> 7, k = rr & 127;
        if (n < 128)      v = Wq[l*16384 + k*128 + n];
        else if (n < 256) v = Wk[l*32768 + (128+k)*128 + (n-128)];
        else              v = Wv[l*32768 + (128+k)*128 + (n-256)];
        dst = Wn_t + l*49152 + rr;
    }
    *dst = __float2bfloat16(v);
}

// ---------------------------------------------------------------- attention: 2 nodes/block
// Ae LDS staging (cooperative prefetch) + parallel softmax.
__global__ __launch_bounds__(256) void attn_kernel(
    const __hip_bfloat16* __restrict__ E_ln, const __hip_bfloat16* __restrict__ Wt,
    const float* __restrict__ bias_kv,
    float* __restrict__ P, const int* __restrict__ E_idx,
    const float* __restrict__ mask)
{
    int g0 = blockIdx.x * 2;
    int t = threadIdx.x;
    int wave = t >> 6, lane = t & 63, lm = lane & 15, lq = lane >> 4;
    __shared__ __hip_bfloat16 Ae[64*136];     // A tile, pitch 136 bf16
    __shared__ __hip_bfloat16 KVs[60*264];    // K|V rows, pitch 264 bf16
    __shared__ float Qs[2*H];
    __shared__ float att_s[2*120];
    __shared__ float mv_s[60];
    __shared__ int   nbr[60];

    const __hip_bfloat16* hebase = E_ln + (size_t)g0*KNB*H;
    for (int q = t; q < 960; q += 256) {
        int r = q >> 4, c8 = (q & 15) * 8;
        *(s8v*)&Ae[r*136 + c8] = *(const s8v*)&hebase[r*H + c8];
    }
    if (t < 60) {
        int gn = g0 + t/30;
        int b = gn / NN;
        int idx = E_idx[gn*KNB + (t%30)];
        nbr[t]  = b*NN + idx;
        mv_s[t] = mask[gn] * mask[b*NN + idx];
    }
    {
        int node = t >> 7, c = t & 127;
        Qs[t] = P[(size_t)(g0+node)*384 + c];
    }
    __syncthreads();

    // MFMA: wave w handles n-tiles 4w..4w+3; epilogue fuses bias+gather
    {
        int cb = wave*64 + lm;
        const __hip_bfloat16* wb = Wt + (size_t)cb*H + lq*8;
        s8v bfr[4][4];
#pragma unroll
        for (int nt = 0; nt < 4; nt++)
#pragma unroll
            for (int ks = 0; ks < 4; ks++)
                bfr[nt][ks] = *(const s8v*)(wb + nt*16*H + ks*32);
        float bias0 = bias_kv[cb], bias1 = bias_kv[cb+16];
        float bias2 = bias_kv[cb+32], bias3 = bias_kv[cb+48];
#pragma unroll
        for (int mt = 0; mt < 4; mt++) {
            f4v a0 = {0.f,0.f,0.f,0.f}, a1 = a0, a2 = a0, a3 = a0;
#pragma unroll
            for (int ks = 0; ks < 4; ks++) {
                s8v af = *(const s8v*)&Ae[(mt*16+lm)*136 + ks*32 + lq*8];
                a0 = __builtin_amdgcn_mfma_f32_16x16x32_bf16(af, bfr[0][ks], a0, 0,0,0);
                a1 = __builtin_amdgcn_mfma_f32_16x16x32_bf16(af, bfr[1][ks], a1, 0,0,0);
                a2 = __builtin_amdgcn_mfma_f32_16x16x32_bf16(af, bfr[2][ks], a2, 0,0,0);
                a3 = __builtin_amdgcn_mfma_f32_16x16x32_bf16(af, bfr[3][ks], a3, 0,0,0);
            }
            int rbase = mt*16 + lq*4;
#pragma unroll
            for (int r = 0; r < 4; r++) {
                int row = rbase + r;
                if (row < 60) {
                    const float* pb = P + (size_t)nbr[row]*384 + 128 + cb;
                    KVs[row*264 + cb     ] = __float2bfloat16(a0[r] + bias0 + pb[0]);
                    KVs[row*264 + cb + 16] = __float2bfloat16(a1[r] + bias1 + pb[16]);
                    KVs[row*264 + cb + 32] = __float2bfloat16(a2[r] + bias2 + pb[32]);
                    KVs[row*264 + cb + 48] = __float2bfloat16(a3[r] + bias3 + pb[48]);
                }
            }
        }
    }
    __syncthreads();

    // logits (b128 LDS reads)
    if (t < 240) {
        int node = t / 120, tt = t % 120;
        int h = tt / 30, kk = tt % 30;
        int r = node*30 + kk;
        const uint4* kp = (const uint4*)&KVs[r*264 + h*32];
        const float* qp = &Qs[node*128 + h*32];
        float a = 0.f;
#pragma unroll
        for (int j = 0; j < 4; j++) {
            uint4 u = kp[j];
            const float* q8 = qp + j*8;
            a += q8[0]*bf_lo(u.x) + q8[1]*bf_hi(u.x)
               + q8[2]*bf_lo(u.y) + q8[3]*bf_hi(u.y)
               + q8[4]*bf_lo(u.z) + q8[5]*bf_hi(u.z)
               + q8[6]*bf_lo(u.w) + q8[7]*bf_hi(u.w);
        }
        att_s[node*120 + h*30 + kk] =
            (mv_s[r] > 0.f) ? a*0.17677669529663687f : -3.4028235e38f;
    }
    __syncthreads();

    // parallel softmax: wave w = node w (w<2), 16 lanes per head, 2 entries/lane
    if (wave < 2) {
        int node = wave, h = lq, j = lm;
        float* ap = &att_s[node*120 + h*30];
        const float* mp = &mv_s[node*30];
        float a0 = ap[j];
        float a1 = (j+16 < KNB) ? ap[j+16] : -3.4028235e38f;
        float mx = fmaxf(a0, a1);
#pragma unroll
        for (int m = 1; m < 16; m <<= 1) mx = fmaxf(mx, __shfl_xor(mx, m, 64));
        float e0 = __expf(a0 - mx);
        float e1 = (j+16 < KNB) ? __expf(a1 - mx) : 0.f;
        float s = e0 + e1;
#pragma unroll
        for (int m = 1; m < 16; m <<= 1) s += __shfl_xor(s, m, 64);
        float inv = 1.0f / s;
        ap[j] = e0 * inv * mp[j];
        if (j+16 < KNB) ap[j+16] = e1 * inv * mp[j+16];
    }
    __syncthreads();

    // upd = sum_k att * V; write into P Q-slots
    {
        int node = t >> 7, c = t & 127;
        const float* ap = &att_s[node*120 + (c>>5)*30];
        float u = 0.f;
        for (int kk = 0; kk < KNB; kk++)
            u += ap[kk] * __bfloat162float(KVs[(node*30+kk)*264 + 128 + c]);
        P[(size_t)(g0+node)*384 + c] = u;
    }
}

// ---------------------------------------------------------------- Wo + LN1 + FF + LN2 (+ next-layer node proj), MFMA
// 16 rows/block (grid 375) — R7-validated configuration.
__global__ __launch_bounds__(256) void post_kernel(
    float* __restrict__ hv, float* __restrict__ P,
    const float* __restrict__ mask,
    const __hip_bfloat16* __restrict__ Wo_t,
    const float* __restrict__ ln1g, const float* __restrict__ ln1b,
    const float* __restrict__ ln2g, const float* __restrict__ ln2b,
    const __hip_bfloat16* __restrict__ Wf1_t, const float* __restrict__ bf1,
    const __hip_bfloat16* __restrict__ Wf2_t, const float* __restrict__ bf2,
    const __hip_bfloat16* __restrict__ Wn_t)
{
    int row0 = blockIdx.x * 16;
    int t = threadIdx.x;
    int wave = t >> 6, lane = t & 63, lm = lane & 15, lq = lane >> 4;

    __shared__ __hip_bfloat16 Aus[16*136];   // upd bf16
    __shared__ float xs[16*132];             // fp32 working rows
    __shared__ __hip_bfloat16 ys[16*136];    // LN1 out bf16
    __shared__ __hip_bfloat16 t1[16*520];    // relu(FF1) bf16
    __shared__ __hip_bfloat16 zs[16*136];    // hv_out bf16
    __shared__ float ps[256], pq[256];
    __shared__ float mu_s[16], rs_s[16];

    for (int q = t; q < 2048; q += 256) {
        int r = q >> 7, c = q & 127;
        Aus[r*136+c] = __float2bfloat16(P[(size_t)(row0+r)*384 + c]);
    }
    __syncthreads();

    for (int ntl = 0; ntl < 2; ntl++) {
        int nt = wave*2 + ntl;
        f4v acc = {0.f,0.f,0.f,0.f};
#pragma unroll
        for (int ks = 0; ks < 4; ks++) {
            s8v af = *(const s8v*)&Aus[lm*136 + ks*32 + lq*8];
            s8v bf = *(const s8v*)&Wo_t[(nt*16+lm)*128 + ks*32 + lq*8];
            acc = __builtin_amdgcn_mfma_f32_16x16x32_bf16(af, bf, acc, 0,0,0);
        }
        int cc = nt*16 + lm;
#pragma unroll
        for (int r = 0; r < 4; r++) {
            int rr = lq*4 + r;
            xs[rr*132+cc] = hv[(size_t)(row0+rr)*128 + cc] + acc[r];
        }
    }
    __syncthreads();

    {
        int r = t >> 4, s = t & 15;
        float4 a = *(const float4*)&xs[r*132 + s*8];
        float4 b = *(const float4*)&xs[r*132 + s*8 + 4];
        ps[t] = a.x+a.y+a.z+a.w + b.x+b.y+b.z+b.w;
        pq[t] = a.x*a.x+a.y*a.y+a.z*a.z+a.w*a.w + b.x*b.x+b.y*b.y+b.z*b.z+b.w*b.w;
    }
    __syncthreads();
    if (t < 16) {
        float sm = 0.f, sq = 0.f;
        for (int s = 0; s < 16; s++) { sm += ps[t*16+s]; sq += pq[t*16+s]; }
        float mu = sm*(1.0f/H);
        mu_s[t] = mu;
        rs_s[t] = rsqrtf(sq*(1.0f/H) - mu*mu + LN_EPS);
    }
    __syncthreads();
    for (int q = t; q < 2048; q += 256) {
        int r = q >> 7, c = q & 127;
        float v = ln1g[c]*(xs[r*132+c]-mu_s[r])*rs_s[r] + ln1b[c];
        xs[r*132+c] = v;
        ys[r*136+c] = __float2bfloat16(v);
    }
    __syncthreads();

    for (int ntl = 0; ntl < 8; ntl++) {
        int nt = wave*8 + ntl;
        f4v acc = {0.f,0.f,0.f,0.f};
#pragma unroll
        for (int ks = 0; ks < 4; ks++) {
            s8v af = *(const s8v*)&ys[lm*136 + ks*32 + lq*8];
            s8v bf = *(const s8v*)&Wf1_t[(size_t)(nt*16+lm)*128 + ks*32 + lq*8];
            acc = __builtin_amdgcn_mfma_f32_16x16x32_bf16(af, bf, acc, 0,0,0);
        }
        int cc = nt*16 + lm;
        float b = bf1[cc];
#pragma unroll
        for (int r = 0; r < 4; r++)
            t1[(lq*4+r)*520 + cc] = __float2bfloat16(fmaxf(acc[r]+b, 0.f));
    }
    __syncthreads();

    for (int ntl = 0; ntl < 2; ntl++) {
        int nt = wave*2 + ntl;
        f4v acc = {0.f,0.f,0.f,0.f};
#pragma unroll
        for (int ks = 0; ks < 16; ks++) {
            s8v af = *(const s8v*)&t1[lm*520 + ks*32 + lq*8];
            s8v bf = *(const s8v*)&Wf2_t[(size_t)(nt*16+lm)*512 + ks*32 + lq*8];
            acc = __builtin_amdgcn_mfma_f32_16x16x32_bf16(af, bf, acc, 0,0,0);
        }
        int cc = nt*16 + lm;
        float b = bf2[cc];
#pragma unroll
        for (int r = 0; r < 4; r++) {
            int rr = lq*4 + r;
            xs[rr*132+cc] = xs[rr*132+cc] + acc[r] + b;
        }
    }
    __syncthreads();

    {
        int r = t >> 4, s = t & 15;
        float4 a = *(const float4*)&xs[r*132 + s*8];
        float4 b = *(const float4*)&xs[r*132 + s*8 + 4];
        ps[t] = a.x+a.y+a.z+a.w + b.x+b.y+b.z+b.w;
        pq[t] = a.x*a.x+a.y*a.y+a.z*a.z+a.w*a.w + b.x*b.x+b.y*b.y+b.z*b.z+b.w*b.w;
    }
    __syncthreads();
    if (t < 16) {
        float sm = 0.f, sq = 0.f;
        for (int s = 0; s < 16; s++) { sm += ps[t*16+s]; sq += pq[t*16+s]; }
        float mu = sm*(1.0f/H);
        mu_s[t] = mu;
        rs_s[t] = rsqrtf(sq*(1.0f/H) - mu*mu + LN_EPS);
    }
    __syncthreads();
    for (int q = t; q < 2048; q += 256) {
        int r = q >> 7, c = q & 127;
        float v = mask[row0+r]*(ln2g[c]*(xs[r*132+c]-mu_s[r])*rs_s[r] + ln2b[c]);
        hv[(size_t)(row0+r)*128 + c] = v;
        zs[r*136+c] = __float2bfloat16(v);
    }
    __syncthreads();

    if (Wn_t) {
        for (int ntl = 0; ntl < 6; ntl++) {
            int nt = wave*6 + ntl;
            f4v acc = {0.f,0.f,0.f,0.f};
#pragma unroll
            for (int ks = 0; ks < 4; ks++) {
                s8v af = *(const s8v*)&zs[lm*136 + ks*32 + lq*8];
                s8v bf = *(const s8v*)&Wn_t[(size_t)(nt*16+lm)*128 + ks*32 + lq*8];
                acc = __builtin_amdgcn_mfma_f32_16x16x32_bf16(af, bf, acc, 0,0,0);
            }
            int cc = nt*16 + lm;
#pragma unroll
            for (int r = 0; r < 4; r++)
                P[(size_t)(row0 + lq*4 + r)*384 + cc] = acc[r];
        }
    }
}

// ---------------------------------------------------------------- final projection
__global__ __launch_bounds__(64) void out_kernel(
    const float* __restrict__ hv, const float* __restrict__ W_out,
    const float* __restrict__ b_out, float* __restrict__ out)
{
    int row = blockIdx.x;
    int t = threadIdx.x;
    float a = hv[row*H+t]*W_out[t] + hv[row*H+t+64]*W_out[t+64];
#pragma unroll
    for (int s = 32; s > 0; s >>= 1) a += __shfl_down(a, s, 64);
    if (t == 0) out[row] = a + b_out[0];
}

// ---------------------------------------------------------------- launch
extern "C" void kernel_launch(void* const* d_in, const int* in_sizes, int n_in,
                              void* d_out, int out_size, void* d_ws, size_t ws_size,
                              hipStream_t stream)
{
    const float* X      = (const float*)d_in[0];
    const float* V      = (const float*)d_in[1];
    const float* mask   = (const float*)d_in[2];
    const float* W_v    = (const float*)d_in[3];
    const float* b_v    = (const float*)d_in[4];
    const float* W_e    = (const float*)d_in[5];
    const float* b_e    = (const float*)d_in[6];
    const float* W_edge = (const float*)d_in[7];
    const float* ln_e_g = (const float*)d_in[8];
    const float* ln_e_b = (const float*)d_in[9];
    const float* Wq     = (const float*)d_in[10];
    const float* Wk     = (const float*)d_in[11];
    const float* Wv_a   = (const float*)d_in[12];
    const float* Wo     = (const float*)d_in[13];
    const float* ln1g   = (const float*)d_in[14];
    const float* ln1b   = (const float*)d_in[15];
    const float* ln2g   = (const float*)d_in[16];
    const float* ln2b   = (const float*)d_in[17];
    const float* Wf1    = (const float*)d_in[18];
    const float* bf1    = (const float*)d_in[19];
    const float* Wf2    = (const float*)d_in[20];
    const float* bf2    = (const float*)d_in[21];
    const float* W_out  = (const float*)d_in[22];
    const float* b_out  = (const float*)d_in[23];
    float* out = (float*)d_out;

    // workspace layout (same as R7)
    char* ws = (char*)d_ws;
    int*            E_idx    = (int*)ws;
    float*          D_nb     = (float*)(ws + 720000);
    __hip_bfloat16* E_ln     = (__hip_bfloat16*)(ws + 1440000);
    float*          hv       = (float*)(ws + 47520000);
    __hip_bfloat16* Wt_kv    = (__hip_bfloat16*)(ws + 50592000);
    float*          bias_kv  = (float*)(ws + 50854144);
    __hip_bfloat16* Wn_t     = (__hip_bfloat16*)(ws + 50858240);
    __hip_bfloat16* Wo_t     = (__hip_bfloat16*)(ws + 51251456);
    __hip_bfloat16* Wf1_t    = (__hip_bfloat16*)(ws + 51382528);
    __hip_bfloat16* Wf2_t    = (__hip_bfloat16*)(ws + 51906816);
    __hip_bfloat16* Wv_t     = (__hip_bfloat16*)(ws + 52431104);
    __hip_bfloat16* W_edge_t = (__hip_bfloat16*)(ws + 52693248);
    float*          P        = (float*)(ws + 53664000);

    topk_kernel<<<NROWS, 256, 0, stream>>>(X, mask, E_idx, D_nb);
    wprep_edge_kernel<<<16, 256, 0, stream>>>(W_edge, W_edge_t);
    edge_kernel<<<NROWS/2, 256, 0, stream>>>(E_idx, D_nb, W_edge_t, ln_e_g, ln_e_b, E_ln);
    wprep_kv_kernel<<<1024, 128, 0, stream>>>(W_e, b_e, Wk, Wv_a, Wt_kv, bias_kv);
    wprep_post_kernel<<<3072, 256, 0, stream>>>(Wo, Wf1, Wf2, Wq, Wk, Wv_a,
                                                Wo_t, Wf1_t, Wf2_t, Wn_t);
    wprep_v_kernel<<<512, 256, 0, stream>>>(W_v, Wv_t);
    hv_init_kernel<<<NROWS/16, 256, 0, stream>>>(V, Wv_t, b_v, hv, Wn_t, P);

    for (int l = 0; l < 4; l++) {
        attn_kernel<<<NROWS/2, 256, 0, stream>>>(
            E_ln, Wt_kv + (size_t)l*256*H, bias_kv + l*256, P, E_idx, mask);
        post_kernel<<<NROWS/16, 256, 0, stream>>>(
            hv, P, mask, Wo_t + l*16384,
            ln1g + l*H, ln1b + l*H, ln2g + l*H, ln2b + l*H,
            Wf1_t + (size_t)l*65536, bf1 + l*FFH,
            Wf2_t + (size_t)l*65536, bf2 + l*H,
            (l < 3) ? (Wn_t + (size_t)(l+1)*49152) : (const __hip_bfloat16*)nullptr);
    }
    out_kernel<<<NROWS, 64, 0, stream>>>(hv, W_out, b_out, out);
}